// Round 6
// baseline (258.487 us; speedup 1.0000x reference)
//
#include <hip/hip_runtime.h>
#include <math.h>

#define TT 1024
#define BB 4
#define HH 1024
#define NHH 32
#define CL 64
#define NCH (TT/CL)

typedef unsigned short u16;
typedef __attribute__((ext_vector_type(8))) short short8;
typedef __attribute__((ext_vector_type(8))) unsigned short u16x8;
typedef __attribute__((ext_vector_type(4))) float floatx4;

__device__ __forceinline__ float sigmoidf_(float x){ return 1.f/(1.f+expf(-x)); }
__device__ __forceinline__ u16 f2b(float f){
  union { float f; unsigned u; } x; x.f = f;
  unsigned r = x.u + 0x7FFFu + ((x.u >> 16) & 1u);
  return (u16)(r >> 16);
}
__device__ __forceinline__ float b2f(u16 v){
  union { unsigned u; float f; } x; x.u = ((unsigned)v) << 16;
  return x.f;
}

// ---------------- cast fp32 -> bf16 (x, [Wq|Wk|Wv|Wbeta|Wmix], Wout) + rope table ----------------
__global__ __launch_bounds__(256) void cast_all_k(
    const float* __restrict__ x, const float* __restrict__ Wq, const float* __restrict__ Wk,
    const float* __restrict__ Wv, const float* __restrict__ Wbeta, const float* __restrict__ Wmix,
    const float* __restrict__ Wout,
    u16* __restrict__ x_bf, u16* __restrict__ Wf, u16* __restrict__ Wout_bf,
    float* __restrict__ ct, float* __restrict__ st)
{
  int gid = blockIdx.x*256 + threadIdx.x;
  if (gid < 16384) {   // rope table: t=gid>>4, j=gid&15
    int t = gid >> 4, j = gid & 15;
    float invf = powf(10000.f, -(float)j/16.f);
    float ang = (float)t * invf;
    ct[gid] = cosf(ang);
    st[gid] = sinf(ang);
  }
  size_t e = (size_t)gid*4;   // 8519680 total elems
  const float* src; u16* dst; size_t so, dof;
  if      (e < 4194304) { src=x;     dst=x_bf;    so=e;          dof=so; }
  else if (e < 5242880) { src=Wq;    dst=Wf;      so=e-4194304;  dof=so; }
  else if (e < 6291456) { src=Wk;    dst=Wf;      so=e-5242880;  dof=so+1048576; }
  else if (e < 7340032) { src=Wv;    dst=Wf;      so=e-6291456;  dof=so+2097152; }
  else if (e < 7405568) { src=Wbeta; dst=Wf;      so=e-7340032;  dof=so+3145728; }
  else if (e < 7471104) { src=Wmix;  dst=Wf;      so=e-7405568;  dof=so+3211264; }
  else                  { src=Wout;  dst=Wout_bf; so=e-7471104;  dof=so; }
  float4 f = *reinterpret_cast<const float4*>(src + so);
  ushort4 u; u.x=f2b(f.x); u.y=f2b(f.y); u.z=f2b(f.z); u.w=f2b(f.w);
  *reinterpret_cast<ushort4*>(dst + dof) = u;
}

// ---------------- fused QKV+beta/mix GEMM, N=3200, rope/elu/sigmoid/softmax epilogue ----------
// 1-D grid 800, row-fastest: by=id&31, bx=id>>5. __launch_bounds__(256,5): 5 blocks/CU.
__global__ __launch_bounds__(256, 5) void gemm_qkv_k(
    const u16* __restrict__ A, const u16* __restrict__ W,
    const float* __restrict__ ct, const float* __restrict__ st,
    const float* __restrict__ bbeta, const float* __restrict__ bmix,
    u16* __restrict__ qkv, float* __restrict__ betag, float* __restrict__ mixg)
{
  __shared__ u16 As[128*64];
  __shared__ u16 Ws[128*64];
  const int tid = threadIdx.x;
  const int lane = tid & 63;
  const int wave = tid >> 6;
  const int wm = wave >> 1, wn = wave & 1;
  const int id = blockIdx.x;
  const int row0 = (id & 31)*128, bx = id >> 5, col0 = bx*128;
  const int lr = lane & 15, lkg = lane >> 4;

  floatx4 acc[4][4];
  #pragma unroll
  for (int mt=0; mt<4; ++mt)
    #pragma unroll
    for (int nt=0; nt<4; ++nt)
      acc[mt][nt] = (floatx4){0.f,0.f,0.f,0.f};

  for (int k0 = 0; k0 < 1024; k0 += 64) {
    __syncthreads();
    #pragma unroll
    for (int it = 0; it < 4; ++it) {
      int li  = it*256 + tid;
      int row = li >> 3, ckp = li & 7;
      int ck  = ckp ^ (row & 7);
      const u16* ga = A + (size_t)(row0+row)*1024 + k0 + ck*8;
      const u16* gw = W + (size_t)(col0+row)*1024 + k0 + ck*8;
      __builtin_amdgcn_global_load_lds(
          (const __attribute__((address_space(1))) void*)ga,
          (__attribute__((address_space(3))) void*)(As + (size_t)(li & ~63)*8), 16, 0, 0);
      __builtin_amdgcn_global_load_lds(
          (const __attribute__((address_space(1))) void*)gw,
          (__attribute__((address_space(3))) void*)(Ws + (size_t)(li & ~63)*8), 16, 0, 0);
    }
    __syncthreads();
    #pragma unroll
    for (int kk = 0; kk < 64; kk += 32) {
      short8 af[4], wf[4];
      const int ckw = (kk >> 3) + lkg;
      #pragma unroll
      for (int t = 0; t < 4; ++t) {
        int rowA = wm*64 + t*16 + lr;
        int rowW = wn*64 + t*16 + lr;
        af[t] = *reinterpret_cast<const short8*>(As + rowA*64 + (ckw ^ (rowA & 7))*8);
        wf[t] = *reinterpret_cast<const short8*>(Ws + rowW*64 + (ckw ^ (rowW & 7))*8);
      }
      #pragma unroll
      for (int mt = 0; mt < 4; ++mt)
        #pragma unroll
        for (int nt = 0; nt < 4; ++nt)
          acc[mt][nt] = __builtin_amdgcn_mfma_f32_16x16x32_bf16(af[mt], wf[nt], acc[mt][nt], 0, 0, 0);
    }
  }
  if (bx < 16) {
    // q/k region: rope + elu+1
    #pragma unroll
    for (int mt = 0; mt < 4; ++mt) {
      #pragma unroll
      for (int r = 0; r < 4; ++r) {
        int row = row0 + wm*64 + mt*16 + lkg*4 + r;
        int t = row & (TT-1);
        float c_ = ct[t*16 + lr], s_ = st[t*16 + lr];
        #pragma unroll
        for (int nt = 0; nt < 4; nt += 2) {
          float u1 = acc[mt][nt][r], u2 = acc[mt][nt+1][r];
          float r1 = u1*c_ - u2*s_;
          float r2 = u1*s_ + u2*c_;
          r1 = r1 > 0.f ? r1+1.f : expf(r1);
          r2 = r2 > 0.f ? r2+1.f : expf(r2);
          int col = col0 + wn*64 + nt*16 + lr;
          qkv[(size_t)row*3072 + col]      = f2b(r1);
          qkv[(size_t)row*3072 + col + 16] = f2b(r2);
        }
      }
    }
  } else if (bx < 24) {
    // v region: passthrough bf16
    #pragma unroll
    for (int mt = 0; mt < 4; ++mt)
      #pragma unroll
      for (int r = 0; r < 4; ++r) {
        int row = row0 + wm*64 + mt*16 + lkg*4 + r;
        #pragma unroll
        for (int nt = 0; nt < 4; ++nt) {
          int col = col0 + wn*64 + nt*16 + lr;
          qkv[(size_t)row*3072 + col] = f2b(acc[mt][nt][r]);
        }
      }
  } else {
    // beta (wn=0) / mix (wn=1), cols 3072..3199. cidx = nt*16+lr = h*2+m.
    #pragma unroll
    for (int mt = 0; mt < 4; ++mt)
      #pragma unroll
      for (int r = 0; r < 4; ++r) {
        int row = row0 + wm*64 + mt*16 + lkg*4 + r;
        #pragma unroll
        for (int nt = 0; nt < 4; ++nt) {
          int cidx = nt*16 + lr;
          float v = acc[mt][nt][r];
          if (wn == 0) {
            float bv = sigmoidf_(v + bbeta[cidx]);
            betag[(size_t)row*64 + cidx] = fminf(fmaxf(bv, 0.85f), 0.9995f);
          } else {
            float a = v + bmix[cidx];
            float o = __shfl_xor(a, 1);
            float e = expf(a - fmaxf(a, o));
            float es = e + __shfl_xor(e, 1);
            mixg[(size_t)row*64 + cidx] = e/es;
          }
        }
      }
  }
}

// ---------------- out-projection: z = y @ Wout^T + bout + x (fp32, full K) ----------------
// 128x64 tiles, 1-D grid 512: row=id&31, col=id>>5. 4 waves each own 32 rows x 64 cols.
__global__ __launch_bounds__(256, 5) void gemm_out_k(
    const u16* __restrict__ A, const u16* __restrict__ W,
    const float* __restrict__ xr, const float* __restrict__ bout,
    float* __restrict__ Z)
{
  __shared__ u16 As[128*64];
  __shared__ u16 Ws[64*64];
  const int tid = threadIdx.x;
  const int lane = tid & 63;
  const int wave = tid >> 6;
  const int id = blockIdx.x;
  const int row0 = (id & 31)*128, col0 = (id >> 5)*64;
  const int lr = lane & 15, lkg = lane >> 4;
  floatx4 acc[2][4];
  #pragma unroll
  for (int mt=0; mt<2; ++mt)
    #pragma unroll
    for (int nt=0; nt<4; ++nt)
      acc[mt][nt] = (floatx4){0.f,0.f,0.f,0.f};
  for (int k0 = 0; k0 < 1024; k0 += 64) {
    __syncthreads();
    #pragma unroll
    for (int it = 0; it < 4; ++it) {
      int li  = it*256 + tid;
      int row = li >> 3, ckp = li & 7;
      int ck  = ckp ^ (row & 7);
      const u16* ga = A + (size_t)(row0+row)*1024 + k0 + ck*8;
      __builtin_amdgcn_global_load_lds(
          (const __attribute__((address_space(1))) void*)ga,
          (__attribute__((address_space(3))) void*)(As + (size_t)(li & ~63)*8), 16, 0, 0);
    }
    #pragma unroll
    for (int it = 0; it < 2; ++it) {
      int li  = it*256 + tid;
      int row = li >> 3, ckp = li & 7;
      int ck  = ckp ^ (row & 7);
      const u16* gw = W + (size_t)(col0+row)*1024 + k0 + ck*8;
      __builtin_amdgcn_global_load_lds(
          (const __attribute__((address_space(1))) void*)gw,
          (__attribute__((address_space(3))) void*)(Ws + (size_t)(li & ~63)*8), 16, 0, 0);
    }
    __syncthreads();
    #pragma unroll
    for (int kk = 0; kk < 64; kk += 32) {
      short8 af[2], wf[4];
      const int ckw = (kk >> 3) + lkg;
      #pragma unroll
      for (int t = 0; t < 2; ++t) {
        int rowA = wave*32 + t*16 + lr;
        af[t] = *reinterpret_cast<const short8*>(As + rowA*64 + (ckw ^ (rowA & 7))*8);
      }
      #pragma unroll
      for (int t = 0; t < 4; ++t) {
        int rowW = t*16 + lr;
        wf[t] = *reinterpret_cast<const short8*>(Ws + rowW*64 + (ckw ^ (rowW & 7))*8);
      }
      #pragma unroll
      for (int mt = 0; mt < 2; ++mt)
        #pragma unroll
        for (int nt = 0; nt < 4; ++nt)
          acc[mt][nt] = __builtin_amdgcn_mfma_f32_16x16x32_bf16(af[mt], wf[nt], acc[mt][nt], 0, 0, 0);
    }
  }
  #pragma unroll
  for (int mt = 0; mt < 2; ++mt)
    #pragma unroll
    for (int r = 0; r < 4; ++r) {
      int row = row0 + wave*32 + mt*16 + lkg*4 + r;
      #pragma unroll
      for (int nt = 0; nt < 4; ++nt) {
        int col = col0 + nt*16 + lr;
        Z[(size_t)row*HH + col] = acc[mt][nt][r] + bout[col] + xr[(size_t)row*HH + col];
      }
    }
}

// ---------------- scan pass 1: per-chunk deltas via MFMA ----------------
__global__ __launch_bounds__(256) void scan_delta_k(
    const u16* __restrict__ qkv, const float* __restrict__ betag,
    float* __restrict__ dS, float* __restrict__ dK,
    float* __restrict__ pLg, float* __restrict__ pg)
{
  __shared__ __align__(16) u16 K2T[2][32][72];
  __shared__ __align__(16) u16 VT[32][72];
  __shared__ float bets[2][64], pbuf[2][64], wjs[2][64], pLs[2];
  const int ch = blockIdx.x, h = blockIdx.y, b = blockIdx.z;
  const int bh = b*NHH + h;
  const int tid = threadIdx.x;
  const int t0 = ch*CL;
  const int j = tid >> 2, oct = tid & 3;
  size_t rowbase = (size_t)(b*TT + t0 + j)*3072 + h*32 + oct*8;
  u16x8 k8 = *reinterpret_cast<const u16x8*>(qkv + rowbase + 1024);
  u16x8 v8 = *reinterpret_cast<const u16x8*>(qkv + rowbase + 2048);
  if (tid < 128) {
    int m = tid & 1, tl = tid >> 1;
    bets[m][tl] = betag[(size_t)(b*TT + t0 + tl)*64 + h*2 + m];
  }
  #pragma unroll
  for (int dd = 0; dd < 8; ++dd) VT[oct*8+dd][j] = v8[dd];
  __syncthreads();
  if (tid < 128) {
    int m = tid >> 6, l = tid & 63;
    float p = bets[m][l];
    #pragma unroll
    for (int off = 1; off < 64; off <<= 1) {
      float o = __shfl_up(p, off);
      if (l >= off) p *= o;
    }
    pbuf[m][l] = p;
    if (l == 63) pLs[m] = p;
  }
  __syncthreads();
  if (tid < 128) {
    int m = tid >> 6, l = tid & 63;
    wjs[m][l] = pLs[m] / pbuf[m][l];
    pg[(((size_t)bh*NCH + ch)*2 + m)*64 + l] = pbuf[m][l];
  }
  if (tid < 2) pLg[((size_t)bh*NCH + ch)*2 + tid] = pLs[tid];
  __syncthreads();
  float w0 = wjs[0][j], w1 = wjs[1][j];
  #pragma unroll
  for (int dd = 0; dd < 8; ++dd) {
    float kv = b2f(k8[dd]);
    K2T[0][oct*8+dd][j] = f2b(kv*w0);
    K2T[1][oct*8+dd][j] = f2b(kv*w1);
  }
  __syncthreads();
  {
    const int wv = tid >> 6, lane = tid & 63, lr = lane & 15, kg = lane >> 4;
    const int m = wv >> 1, mt = wv & 1;
    floatx4 a0 = (floatx4){0.f,0.f,0.f,0.f}, a1 = (floatx4){0.f,0.f,0.f,0.f};
    #pragma unroll
    for (int ks = 0; ks < 2; ++ks) {
      short8 af = *reinterpret_cast<const short8*>(&K2T[m][mt*16 + lr][ks*32 + kg*8]);
      short8 b0 = *reinterpret_cast<const short8*>(&VT[lr][ks*32 + kg*8]);
      short8 b1 = *reinterpret_cast<const short8*>(&VT[16 + lr][ks*32 + kg*8]);
      a0 = __builtin_amdgcn_mfma_f32_16x16x32_bf16(af, b0, a0, 0, 0, 0);
      a1 = __builtin_amdgcn_mfma_f32_16x16x32_bf16(af, b1, a1, 0, 0, 0);
    }
    size_t base = (((size_t)bh*NCH + ch)*2 + m)*1024;
    #pragma unroll
    for (int r = 0; r < 4; ++r) {
      int d = mt*16 + kg*4 + r;
      dS[base + d*32 + lr]      = a0[r];
      dS[base + d*32 + 16 + lr] = a1[r];
    }
  }
  if (tid < 64) {
    int m = tid >> 5, d = tid & 31;
    float s = 0.f;
    #pragma unroll
    for (int g = 0; g < 8; ++g) {
      u16x8 kk = *reinterpret_cast<const u16x8*>(&K2T[m][d][g*8]);
      #pragma unroll
      for (int dd = 0; dd < 8; ++dd) s += b2f(kk[dd]);
    }
    dK[(((size_t)bh*NCH + ch)*2 + m)*32 + d] = s;
  }
}

// ---------------- scan pass 2: prefix scan across chunks ----------------
__global__ __launch_bounds__(256) void scan_state_k(
    float* dSS0, float* dKK0, const float* __restrict__ pLg)
{
  const int bhm = blockIdx.x >> 2, part = blockIdx.x & 3;
  const int bh = bhm >> 1, m = bhm & 1;
  const int idx = part*256 + threadIdx.x;
  float pls[NCH], dv[NCH];
  #pragma unroll
  for (int ch = 0; ch < NCH; ++ch) pls[ch] = pLg[((size_t)bh*NCH + ch)*2 + m];
  #pragma unroll
  for (int ch = 0; ch < NCH; ++ch) dv[ch] = dSS0[(((size_t)bh*NCH + ch)*2 + m)*1024 + idx];
  float S = 0.f;
  #pragma unroll
  for (int ch = 0; ch < NCH; ++ch) {
    dSS0[(((size_t)bh*NCH + ch)*2 + m)*1024 + idx] = S;
    S = fmaf(pls[ch], S, dv[ch]);
  }
  if (part == 0 && threadIdx.x < 32) {
    int d = threadIdx.x;
    float kv[NCH];
    #pragma unroll
    for (int ch = 0; ch < NCH; ++ch) kv[ch] = dKK0[(((size_t)bh*NCH + ch)*2 + m)*32 + d];
    float K0 = 0.f;
    #pragma unroll
    for (int ch = 0; ch < NCH; ++ch) {
      dKK0[(((size_t)bh*NCH + ch)*2 + m)*32 + d] = K0;
      K0 = fmaf(pls[ch], K0, kv[ch]);
    }
  }
}

// ---------------- scan pass 3: A0=QK^T, Atilde, den, y via MFMA ----------------
__global__ __launch_bounds__(256) void scan_apply_k(
    const u16* __restrict__ qkv, const float* __restrict__ mixg,
    const float* __restrict__ S0g, const float* __restrict__ K0g,
    const float* __restrict__ pg, u16* __restrict__ yb)
{
  __shared__ __align__(16) u16 Qs[64][32], Ks[64][32];
  __shared__ __align__(16) u16 VT[32][72];
  __shared__ __align__(16) u16 At[2][64][72];
  __shared__ __align__(16) u16 S0T[2][2][32][40];
  __shared__ float K0s[2][32];
  __shared__ float pbv[2][64], ipb[2][64], mixs[2][64], coef[2][64];
  const int ch = blockIdx.x, h = blockIdx.y, b = blockIdx.z;
  const int bh = b*NHH + h;
  const int tid = threadIdx.x;
  const int t0 = ch*CL;
  {
    int j = tid >> 2, oct = tid & 3;
    size_t rb = (size_t)(b*TT + t0 + j)*3072 + h*32 + oct*8;
    u16x8 q8 = *reinterpret_cast<const u16x8*>(qkv + rb);
    u16x8 k8 = *reinterpret_cast<const u16x8*>(qkv + rb + 1024);
    u16x8 v8 = *reinterpret_cast<const u16x8*>(qkv + rb + 2048);
    *reinterpret_cast<u16x8*>(&Qs[j][oct*8]) = q8;
    *reinterpret_cast<u16x8*>(&Ks[j][oct*8]) = k8;
    #pragma unroll
    for (int dd = 0; dd < 8; ++dd) VT[oct*8+dd][j] = v8[dd];
  }
  for (int u = tid; u < 2048; u += 256) {
    int m = u >> 10, r = u & 1023, d = r >> 5, c = r & 31;
    float val = S0g[(((size_t)bh*NCH + ch)*2 + m)*1024 + r];
    u16 hv = f2b(val);
    float lo = val - b2f(hv);
    S0T[m][0][c][d] = hv;
    S0T[m][1][c][d] = f2b(lo);
  }
  if (tid < 64) {
    int m = tid >> 5, d = tid & 31;
    K0s[m][d] = K0g[(((size_t)bh*NCH + ch)*2 + m)*32 + d];
  }
  if (tid < 128) {
    int m = tid & 1, i = tid >> 1;
    float p = pg[(((size_t)bh*NCH + ch)*2 + m)*64 + i];
    pbv[m][i] = p;
    ipb[m][i] = 1.f/p;
  } else if (tid < 192) {
    int i = tid - 128;
    size_t rb = (size_t)(b*TT + t0 + i)*64 + h*2;
    mixs[0][i] = mixg[rb];
    mixs[1][i] = mixg[rb+1];
  }
  __syncthreads();
  {
    const int wv = tid >> 6, lane = tid & 63, lr = lane & 15, kg = lane >> 4;
    short8 aq = *reinterpret_cast<const short8*>(&Qs[wv*16 + lr][kg*8]);
    #pragma unroll
    for (int nt = 0; nt < 4; ++nt) {
      short8 bk = *reinterpret_cast<const short8*>(&Ks[nt*16 + lr][kg*8]);
      floatx4 a0 = (floatx4){0.f,0.f,0.f,0.f};
      a0 = __builtin_amdgcn_mfma_f32_16x16x32_bf16(aq, bk, a0, 0, 0, 0);
      int jg = nt*16 + lr;
      float ip0 = ipb[0][jg], ip1 = ipb[1][jg];
      #pragma unroll
      for (int r = 0; r < 4; ++r) {
        int ig = wv*16 + kg*4 + r;
        float val = a0[r];
        bool ok = (jg <= ig);
        At[0][ig][jg] = f2b(ok ? val*ip0 : 0.f);
        At[1][ig][jg] = f2b(ok ? val*ip1 : 0.f);
      }
    }
  }
  __syncthreads();
  if (tid < 128) {
    int m = tid & 1, i = tid >> 1;
    float qK0 = 0.f;
    #pragma unroll
    for (int g = 0; g < 4; ++g) {
      u16x8 qq = *reinterpret_cast<const u16x8*>(&Qs[i][g*8]);
      #pragma unroll
      for (int dd = 0; dd < 8; ++dd) qK0 = fmaf(b2f(qq[dd]), K0s[m][g*8+dd], qK0);
    }
    float As_ = 0.f;
    #pragma unroll
    for (int g = 0; g < 8; ++g) {
      u16x8 aa = *reinterpret_cast<const u16x8*>(&At[m][i][g*8]);
      #pragma unroll
      for (int dd = 0; dd < 8; ++dd) As_ += b2f(aa[dd]);
    }
    float den = pbv[m][i]*(qK0 + As_) + 1e-6f;
    coef[m][i] = mixs[m][i]*pbv[m][i]/den;
  }
  __syncthreads();
  {
    const int wv = tid >> 6, lane = tid & 63, lr = lane & 15, kg = lane >> 4;
    const int i0 = wv*16;
    floatx4 accY[2][2];
    #pragma unroll
    for (int m = 0; m < 2; ++m)
      #pragma unroll
      for (int nt = 0; nt < 2; ++nt)
        accY[m][nt] = (floatx4){0.f,0.f,0.f,0.f};
    short8 aq = *reinterpret_cast<const short8*>(&Qs[i0 + lr][kg*8]);
    #pragma unroll
    for (int m = 0; m < 2; ++m)
      #pragma unroll
      for (int nt = 0; nt < 2; ++nt) {
        short8 bhi = *reinterpret_cast<const short8*>(&S0T[m][0][nt*16 + lr][kg*8]);
        short8 blo = *reinterpret_cast<const short8*>(&S0T[m][1][nt*16 + lr][kg*8]);
        accY[m][nt] = __builtin_amdgcn_mfma_f32_16x16x32_bf16(aq, bhi, accY[m][nt], 0, 0, 0);
        accY[m][nt] = __builtin_amdgcn_mfma_f32_16x16x32_bf16(aq, blo, accY[m][nt], 0, 0, 0);
      }
    #pragma unroll
    for (int ks = 0; ks < 2; ++ks) {
      short8 a0f = *reinterpret_cast<const short8*>(&At[0][i0 + lr][ks*32 + kg*8]);
      short8 a1f = *reinterpret_cast<const short8*>(&At[1][i0 + lr][ks*32 + kg*8]);
      short8 b0 = *reinterpret_cast<const short8*>(&VT[lr][ks*32 + kg*8]);
      short8 b1 = *reinterpret_cast<const short8*>(&VT[16 + lr][ks*32 + kg*8]);
      accY[0][0] = __builtin_amdgcn_mfma_f32_16x16x32_bf16(a0f, b0, accY[0][0], 0, 0, 0);
      accY[0][1] = __builtin_amdgcn_mfma_f32_16x16x32_bf16(a0f, b1, accY[0][1], 0, 0, 0);
      accY[1][0] = __builtin_amdgcn_mfma_f32_16x16x32_bf16(a1f, b0, accY[1][0], 0, 0, 0);
      accY[1][1] = __builtin_amdgcn_mfma_f32_16x16x32_bf16(a1f, b1, accY[1][1], 0, 0, 0);
    }
    #pragma unroll
    for (int r = 0; r < 4; ++r) {
      int i = i0 + kg*4 + r;
      float c0 = coef[0][i], c1 = coef[1][i];
      size_t ob = (size_t)(b*TT + t0 + i)*HH + h*32;
      yb[ob + lr]      = f2b(c0*accY[0][0][r] + c1*accY[1][0][r]);
      yb[ob + 16 + lr] = f2b(c0*accY[0][1][r] + c1*accY[1][1][r]);
    }
  }
}

// ---------------- LayerNorm over rows of z ----------------
__global__ __launch_bounds__(256) void ln_k(
    const float* __restrict__ z, const float* __restrict__ g,
    const float* __restrict__ bta, float* __restrict__ out)
{
  const int row = blockIdx.x;
  const int tid = threadIdx.x;
  size_t o = (size_t)row*HH/4 + tid;
  float4 zv = reinterpret_cast<const float4*>(z)[o];
  float sum = zv.x+zv.y+zv.z+zv.w;
  float sq  = zv.x*zv.x + zv.y*zv.y + zv.z*zv.z + zv.w*zv.w;
  #pragma unroll
  for (int off=1; off<64; off<<=1){ sum += __shfl_xor(sum, off); sq += __shfl_xor(sq, off); }
  __shared__ float s1[4], s2[4];
  int w = tid>>6;
  if ((tid&63)==0){ s1[w]=sum; s2[w]=sq; }
  __syncthreads();
  sum = s1[0]+s1[1]+s1[2]+s1[3];
  sq  = s2[0]+s2[1]+s2[2]+s2[3];
  float mu  = sum * (1.f/1024.f);
  float var = sq * (1.f/1024.f) - mu*mu;
  float rstd = rsqrtf(var + 1e-5f);
  float4 gv = reinterpret_cast<const float4*>(g)[tid];
  float4 bv = reinterpret_cast<const float4*>(bta)[tid];
  float4 ov;
  ov.x = (zv.x-mu)*rstd*gv.x + bv.x;
  ov.y = (zv.y-mu)*rstd*gv.y + bv.y;
  ov.z = (zv.z-mu)*rstd*gv.z + bv.z;
  ov.w = (zv.w-mu)*rstd*gv.w + bv.w;
  reinterpret_cast<float4*>(out)[o] = ov;
}

extern "C" void kernel_launch(void* const* d_in, const int* in_sizes, int n_in,
                              void* d_out, int out_size, void* d_ws, size_t ws_size,
                              hipStream_t stream)
{
  const float* x     = (const float*)d_in[0];
  const float* Wq    = (const float*)d_in[1];
  const float* Wk    = (const float*)d_in[2];
  const float* Wv    = (const float*)d_in[3];
  const float* Wbeta = (const float*)d_in[4];
  const float* bbeta = (const float*)d_in[5];
  const float* Wmix  = (const float*)d_in[6];
  const float* bmix  = (const float*)d_in[7];
  const float* Wout  = (const float*)d_in[8];
  const float* bout  = (const float*)d_in[9];
  const float* ln_g  = (const float*)d_in[10];
  const float* ln_b  = (const float*)d_in[11];
  float* out = (float*)d_out;

  float* ws = (float*)d_ws;
  float* ct      = ws;                       // 16384
  float* st      = ws + 16384;               // 16384
  u16*   x_bf    = (u16*)(ws + 32768);       // 4194304 u16 (reused as y_bf)
  u16*   Wf      = (u16*)(ws + 2129920);     // 3276800 u16
  u16*   Wout_bf = (u16*)(ws + 3768320);     // 1048576 u16
  u16*   qkv     = (u16*)(ws + 4292608);     // 12582912 u16
  float* betag   = ws + 10584064;            // 262144
  float* mixg    = ws + 10846208;            // 262144
  float* dSS0    = ws + 11108352;            // 4194304 (reused as z)
  float* dKK0    = ws + 15302656;            // 131072
  float* pLg     = ws + 15433728;            // 4096
  float* pg      = ws + 15437824;            // 262144
  u16*   y_bf    = x_bf;
  float* z       = dSS0;

  cast_all_k<<<8320, 256, 0, stream>>>(x, Wq, Wk, Wv, Wbeta, Wmix, Wout,
                                       x_bf, Wf, Wout_bf, ct, st);
  gemm_qkv_k<<<800, 256, 0, stream>>>(x_bf, Wf, ct, st, bbeta, bmix, qkv, betag, mixg);
  dim3 gscan(NCH, 32, 4);
  scan_delta_k<<<gscan, 256, 0, stream>>>(qkv, betag, dSS0, dKK0, pLg, pg);
  scan_state_k<<<1024, 256, 0, stream>>>(dSS0, dKK0, pLg);
  scan_apply_k<<<gscan, 256, 0, stream>>>(qkv, mixg, dSS0, dKK0, pg, y_bf);
  gemm_out_k<<<512, 256, 0, stream>>>(y_bf, Wout_bf, x, bout, z);
  ln_k<<<4096, 256, 0, stream>>>(z, ln_g, ln_b, out);
}

// Round 7
// 204.863 us; speedup vs baseline: 1.2618x; 1.2618x over previous
//
#include <hip/hip_runtime.h>
#include <math.h>

#define TT 1024
#define BB 4
#define HH 1024
#define NHH 32
#define CL 64
#define NCH (TT/CL)

typedef unsigned short u16;
typedef __attribute__((ext_vector_type(8))) short short8;
typedef __attribute__((ext_vector_type(8))) unsigned short u16x8;
typedef __attribute__((ext_vector_type(4))) float floatx4;

__device__ __forceinline__ float sigmoidf_(float x){ return 1.f/(1.f+expf(-x)); }
__device__ __forceinline__ u16 f2b(float f){
  union { float f; unsigned u; } x; x.f = f;
  unsigned r = x.u + 0x7FFFu + ((x.u >> 16) & 1u);
  return (u16)(r >> 16);
}
__device__ __forceinline__ float b2f(u16 v){
  union { unsigned u; float f; } x; x.u = ((unsigned)v) << 16;
  return x.f;
}

// ---------------- cast fp32 -> bf16 (x, [Wq|Wk|Wv|Wbeta|Wmix], Wout) + rope table ----------------
__global__ __launch_bounds__(256) void cast_all_k(
    const float* __restrict__ x, const float* __restrict__ Wq, const float* __restrict__ Wk,
    const float* __restrict__ Wv, const float* __restrict__ Wbeta, const float* __restrict__ Wmix,
    const float* __restrict__ Wout,
    u16* __restrict__ x_bf, u16* __restrict__ Wf, u16* __restrict__ Wout_bf,
    float* __restrict__ ct, float* __restrict__ st)
{
  int gid = blockIdx.x*256 + threadIdx.x;
  if (gid < 16384) {   // rope table: t=gid>>4, j=gid&15
    int t = gid >> 4, j = gid & 15;
    float invf = powf(10000.f, -(float)j/16.f);
    float ang = (float)t * invf;
    ct[gid] = cosf(ang);
    st[gid] = sinf(ang);
  }
  size_t e = (size_t)gid*4;   // 8519680 total elems
  const float* src; u16* dst; size_t so, dof;
  if      (e < 4194304) { src=x;     dst=x_bf;    so=e;          dof=so; }
  else if (e < 5242880) { src=Wq;    dst=Wf;      so=e-4194304;  dof=so; }
  else if (e < 6291456) { src=Wk;    dst=Wf;      so=e-5242880;  dof=so+1048576; }
  else if (e < 7340032) { src=Wv;    dst=Wf;      so=e-6291456;  dof=so+2097152; }
  else if (e < 7405568) { src=Wbeta; dst=Wf;      so=e-7340032;  dof=so+3145728; }
  else if (e < 7471104) { src=Wmix;  dst=Wf;      so=e-7405568;  dof=so+3211264; }
  else                  { src=Wout;  dst=Wout_bf; so=e-7471104;  dof=so; }
  float4 f = *reinterpret_cast<const float4*>(src + so);
  ushort4 u; u.x=f2b(f.x); u.y=f2b(f.y); u.z=f2b(f.z); u.w=f2b(f.w);
  *reinterpret_cast<ushort4*>(dst + dof) = u;
}

// ---------------- fused QKV+beta/mix GEMM, N=3200, rope/elu epilogue ----------------
// 1-D grid 800, row-fastest: by=id&31, bx=id>>5 (keeps per-XCD A-tiles fixed in L2).
// Lean epilogue (raw fp32 beta/mix write) keeps VGPR<=100 -> 5 blocks/CU.
__global__ __launch_bounds__(256) void gemm_qkv_k(
    const u16* __restrict__ A, const u16* __restrict__ W,
    const float* __restrict__ ct, const float* __restrict__ st,
    u16* __restrict__ qkv, float* __restrict__ bmraw)
{
  __shared__ u16 As[128*64];
  __shared__ u16 Ws[128*64];
  const int tid = threadIdx.x;
  const int lane = tid & 63;
  const int wave = tid >> 6;
  const int wm = wave >> 1, wn = wave & 1;
  const int id = blockIdx.x;
  const int row0 = (id & 31)*128, bx = id >> 5, col0 = bx*128;
  const int lr = lane & 15, lkg = lane >> 4;

  floatx4 acc[4][4];
  #pragma unroll
  for (int mt=0; mt<4; ++mt)
    #pragma unroll
    for (int nt=0; nt<4; ++nt)
      acc[mt][nt] = (floatx4){0.f,0.f,0.f,0.f};

  for (int k0 = 0; k0 < 1024; k0 += 64) {
    __syncthreads();
    #pragma unroll
    for (int it = 0; it < 4; ++it) {
      int li  = it*256 + tid;
      int row = li >> 3, ckp = li & 7;
      int ck  = ckp ^ (row & 7);
      const u16* ga = A + (size_t)(row0+row)*1024 + k0 + ck*8;
      const u16* gw = W + (size_t)(col0+row)*1024 + k0 + ck*8;
      __builtin_amdgcn_global_load_lds(
          (const __attribute__((address_space(1))) void*)ga,
          (__attribute__((address_space(3))) void*)(As + (size_t)(li & ~63)*8), 16, 0, 0);
      __builtin_amdgcn_global_load_lds(
          (const __attribute__((address_space(1))) void*)gw,
          (__attribute__((address_space(3))) void*)(Ws + (size_t)(li & ~63)*8), 16, 0, 0);
    }
    __syncthreads();
    #pragma unroll
    for (int kk = 0; kk < 64; kk += 32) {
      short8 af[4], wf[4];
      const int ckw = (kk >> 3) + lkg;
      #pragma unroll
      for (int t = 0; t < 4; ++t) {
        int rowA = wm*64 + t*16 + lr;
        int rowW = wn*64 + t*16 + lr;
        af[t] = *reinterpret_cast<const short8*>(As + rowA*64 + (ckw ^ (rowA & 7))*8);
        wf[t] = *reinterpret_cast<const short8*>(Ws + rowW*64 + (ckw ^ (rowW & 7))*8);
      }
      #pragma unroll
      for (int mt = 0; mt < 4; ++mt)
        #pragma unroll
        for (int nt = 0; nt < 4; ++nt)
          acc[mt][nt] = __builtin_amdgcn_mfma_f32_16x16x32_bf16(af[mt], wf[nt], acc[mt][nt], 0, 0, 0);
    }
  }
  if (bx < 16) {
    // q/k region: rope + elu+1
    #pragma unroll
    for (int mt = 0; mt < 4; ++mt) {
      #pragma unroll
      for (int r = 0; r < 4; ++r) {
        int row = row0 + wm*64 + mt*16 + lkg*4 + r;
        int t = row & (TT-1);
        float c_ = ct[t*16 + lr], s_ = st[t*16 + lr];
        #pragma unroll
        for (int nt = 0; nt < 4; nt += 2) {
          float u1 = acc[mt][nt][r], u2 = acc[mt][nt+1][r];
          float r1 = u1*c_ - u2*s_;
          float r2 = u1*s_ + u2*c_;
          r1 = r1 > 0.f ? r1+1.f : expf(r1);
          r2 = r2 > 0.f ? r2+1.f : expf(r2);
          int col = col0 + wn*64 + nt*16 + lr;
          qkv[(size_t)row*3072 + col]      = f2b(r1);
          qkv[(size_t)row*3072 + col + 16] = f2b(r2);
        }
      }
    }
  } else if (bx < 24) {
    // v region: passthrough bf16
    #pragma unroll
    for (int mt = 0; mt < 4; ++mt)
      #pragma unroll
      for (int r = 0; r < 4; ++r) {
        int row = row0 + wm*64 + mt*16 + lkg*4 + r;
        #pragma unroll
        for (int nt = 0; nt < 4; ++nt) {
          int col = col0 + wn*64 + nt*16 + lr;
          qkv[(size_t)row*3072 + col] = f2b(acc[mt][nt][r]);
        }
      }
  } else {
    // beta/mix raw fp32 -> bmraw[row][0..127]
    #pragma unroll
    for (int mt = 0; mt < 4; ++mt)
      #pragma unroll
      for (int r = 0; r < 4; ++r) {
        int row = row0 + wm*64 + mt*16 + lkg*4 + r;
        #pragma unroll
        for (int nt = 0; nt < 4; ++nt) {
          int col = col0 + wn*64 + nt*16 + lr - 3072;
          bmraw[(size_t)row*128 + col] = acc[mt][nt][r];
        }
      }
  }
}

// ---------------- out-projection: z = y @ Wout^T + bout + x (fp32, full K) ----------------
// 128x64 tiles, 1-D grid 512: row=id&31, col=id>>5. 4 waves each own 32 rows x 64 cols.
__global__ __launch_bounds__(256) void gemm_out_k(
    const u16* __restrict__ A, const u16* __restrict__ W,
    const float* __restrict__ xr, const float* __restrict__ bout,
    float* __restrict__ Z)
{
  __shared__ u16 As[128*64];
  __shared__ u16 Ws[64*64];
  const int tid = threadIdx.x;
  const int lane = tid & 63;
  const int wave = tid >> 6;
  const int id = blockIdx.x;
  const int row0 = (id & 31)*128, col0 = (id >> 5)*64;
  const int lr = lane & 15, lkg = lane >> 4;
  floatx4 acc[2][4];
  #pragma unroll
  for (int mt=0; mt<2; ++mt)
    #pragma unroll
    for (int nt=0; nt<4; ++nt)
      acc[mt][nt] = (floatx4){0.f,0.f,0.f,0.f};
  for (int k0 = 0; k0 < 1024; k0 += 64) {
    __syncthreads();
    #pragma unroll
    for (int it = 0; it < 4; ++it) {
      int li  = it*256 + tid;
      int row = li >> 3, ckp = li & 7;
      int ck  = ckp ^ (row & 7);
      const u16* ga = A + (size_t)(row0+row)*1024 + k0 + ck*8;
      __builtin_amdgcn_global_load_lds(
          (const __attribute__((address_space(1))) void*)ga,
          (__attribute__((address_space(3))) void*)(As + (size_t)(li & ~63)*8), 16, 0, 0);
    }
    #pragma unroll
    for (int it = 0; it < 2; ++it) {
      int li  = it*256 + tid;
      int row = li >> 3, ckp = li & 7;
      int ck  = ckp ^ (row & 7);
      const u16* gw = W + (size_t)(col0+row)*1024 + k0 + ck*8;
      __builtin_amdgcn_global_load_lds(
          (const __attribute__((address_space(1))) void*)gw,
          (__attribute__((address_space(3))) void*)(Ws + (size_t)(li & ~63)*8), 16, 0, 0);
    }
    __syncthreads();
    #pragma unroll
    for (int kk = 0; kk < 64; kk += 32) {
      short8 af[2], wf[4];
      const int ckw = (kk >> 3) + lkg;
      #pragma unroll
      for (int t = 0; t < 2; ++t) {
        int rowA = wave*32 + t*16 + lr;
        af[t] = *reinterpret_cast<const short8*>(As + rowA*64 + (ckw ^ (rowA & 7))*8);
      }
      #pragma unroll
      for (int t = 0; t < 4; ++t) {
        int rowW = t*16 + lr;
        wf[t] = *reinterpret_cast<const short8*>(Ws + rowW*64 + (ckw ^ (rowW & 7))*8);
      }
      #pragma unroll
      for (int mt = 0; mt < 2; ++mt)
        #pragma unroll
        for (int nt = 0; nt < 4; ++nt)
          acc[mt][nt] = __builtin_amdgcn_mfma_f32_16x16x32_bf16(af[mt], wf[nt], acc[mt][nt], 0, 0, 0);
    }
  }
  #pragma unroll
  for (int mt = 0; mt < 2; ++mt)
    #pragma unroll
    for (int r = 0; r < 4; ++r) {
      int row = row0 + wave*32 + mt*16 + lkg*4 + r;
      #pragma unroll
      for (int nt = 0; nt < 4; ++nt) {
        int col = col0 + nt*16 + lr;
        Z[(size_t)row*HH + col] = acc[mt][nt][r] + bout[col] + xr[(size_t)row*HH + col];
      }
    }
}

// ---------------- scan pass 1: per-chunk deltas via MFMA (sigmoid fused) ----------------
__global__ __launch_bounds__(256) void scan_delta_k(
    const u16* __restrict__ qkv, const float* __restrict__ bmraw,
    const float* __restrict__ bbeta,
    float* __restrict__ dS, float* __restrict__ dK,
    float* __restrict__ pLg, float* __restrict__ pg)
{
  __shared__ __align__(16) u16 K2T[2][32][72];
  __shared__ __align__(16) u16 VT[32][72];
  __shared__ float bets[2][64], pbuf[2][64], wjs[2][64], pLs[2];
  const int ch = blockIdx.x, h = blockIdx.y, b = blockIdx.z;
  const int bh = b*NHH + h;
  const int tid = threadIdx.x;
  const int t0 = ch*CL;
  const int j = tid >> 2, oct = tid & 3;
  size_t rowbase = (size_t)(b*TT + t0 + j)*3072 + h*32 + oct*8;
  u16x8 k8 = *reinterpret_cast<const u16x8*>(qkv + rowbase + 1024);
  u16x8 v8 = *reinterpret_cast<const u16x8*>(qkv + rowbase + 2048);
  if (tid < 128) {
    int m = tid & 1, tl = tid >> 1;
    float bv = bmraw[(size_t)(b*TT + t0 + tl)*128 + h*2 + m] + bbeta[h*2 + m];
    bets[m][tl] = fminf(fmaxf(sigmoidf_(bv), 0.85f), 0.9995f);
  }
  #pragma unroll
  for (int dd = 0; dd < 8; ++dd) VT[oct*8+dd][j] = v8[dd];
  __syncthreads();
  if (tid < 128) {
    int m = tid >> 6, l = tid & 63;
    float p = bets[m][l];
    #pragma unroll
    for (int off = 1; off < 64; off <<= 1) {
      float o = __shfl_up(p, off);
      if (l >= off) p *= o;
    }
    pbuf[m][l] = p;
    if (l == 63) pLs[m] = p;
  }
  __syncthreads();
  if (tid < 128) {
    int m = tid >> 6, l = tid & 63;
    wjs[m][l] = pLs[m] / pbuf[m][l];
    pg[(((size_t)bh*NCH + ch)*2 + m)*64 + l] = pbuf[m][l];
  }
  if (tid < 2) pLg[((size_t)bh*NCH + ch)*2 + tid] = pLs[tid];
  __syncthreads();
  float w0 = wjs[0][j], w1 = wjs[1][j];
  #pragma unroll
  for (int dd = 0; dd < 8; ++dd) {
    float kv = b2f(k8[dd]);
    K2T[0][oct*8+dd][j] = f2b(kv*w0);
    K2T[1][oct*8+dd][j] = f2b(kv*w1);
  }
  __syncthreads();
  {
    const int wv = tid >> 6, lane = tid & 63, lr = lane & 15, kg = lane >> 4;
    const int m = wv >> 1, mt = wv & 1;
    floatx4 a0 = (floatx4){0.f,0.f,0.f,0.f}, a1 = (floatx4){0.f,0.f,0.f,0.f};
    #pragma unroll
    for (int ks = 0; ks < 2; ++ks) {
      short8 af = *reinterpret_cast<const short8*>(&K2T[m][mt*16 + lr][ks*32 + kg*8]);
      short8 b0 = *reinterpret_cast<const short8*>(&VT[lr][ks*32 + kg*8]);
      short8 b1 = *reinterpret_cast<const short8*>(&VT[16 + lr][ks*32 + kg*8]);
      a0 = __builtin_amdgcn_mfma_f32_16x16x32_bf16(af, b0, a0, 0, 0, 0);
      a1 = __builtin_amdgcn_mfma_f32_16x16x32_bf16(af, b1, a1, 0, 0, 0);
    }
    size_t base = (((size_t)bh*NCH + ch)*2 + m)*1024;
    #pragma unroll
    for (int r = 0; r < 4; ++r) {
      int d = mt*16 + kg*4 + r;
      dS[base + d*32 + lr]      = a0[r];
      dS[base + d*32 + 16 + lr] = a1[r];
    }
  }
  if (tid < 64) {
    int m = tid >> 5, d = tid & 31;
    float s = 0.f;
    #pragma unroll
    for (int g = 0; g < 8; ++g) {
      u16x8 kk = *reinterpret_cast<const u16x8*>(&K2T[m][d][g*8]);
      #pragma unroll
      for (int dd = 0; dd < 8; ++dd) s += b2f(kk[dd]);
    }
    dK[(((size_t)bh*NCH + ch)*2 + m)*32 + d] = s;
  }
}

// ---------------- scan pass 2: prefix scan across chunks ----------------
__global__ __launch_bounds__(256) void scan_state_k(
    float* dSS0, float* dKK0, const float* __restrict__ pLg)
{
  const int bhm = blockIdx.x >> 2, part = blockIdx.x & 3;
  const int bh = bhm >> 1, m = bhm & 1;
  const int idx = part*256 + threadIdx.x;
  float pls[NCH], dv[NCH];
  #pragma unroll
  for (int ch = 0; ch < NCH; ++ch) pls[ch] = pLg[((size_t)bh*NCH + ch)*2 + m];
  #pragma unroll
  for (int ch = 0; ch < NCH; ++ch) dv[ch] = dSS0[(((size_t)bh*NCH + ch)*2 + m)*1024 + idx];
  float S = 0.f;
  #pragma unroll
  for (int ch = 0; ch < NCH; ++ch) {
    dSS0[(((size_t)bh*NCH + ch)*2 + m)*1024 + idx] = S;
    S = fmaf(pls[ch], S, dv[ch]);
  }
  if (part == 0 && threadIdx.x < 32) {
    int d = threadIdx.x;
    float kv[NCH];
    #pragma unroll
    for (int ch = 0; ch < NCH; ++ch) kv[ch] = dKK0[(((size_t)bh*NCH + ch)*2 + m)*32 + d];
    float K0 = 0.f;
    #pragma unroll
    for (int ch = 0; ch < NCH; ++ch) {
      dKK0[(((size_t)bh*NCH + ch)*2 + m)*32 + d] = K0;
      K0 = fmaf(pls[ch], K0, kv[ch]);
    }
  }
}

// ---------------- scan pass 3: A0=QK^T, Atilde, den, y via MFMA (softmax fused) ----------------
__global__ __launch_bounds__(256) void scan_apply_k(
    const u16* __restrict__ qkv, const float* __restrict__ bmraw,
    const float* __restrict__ bmix,
    const float* __restrict__ S0g, const float* __restrict__ K0g,
    const float* __restrict__ pg, u16* __restrict__ yb)
{
  __shared__ __align__(16) u16 Qs[64][32], Ks[64][32];
  __shared__ __align__(16) u16 VT[32][72];
  __shared__ __align__(16) u16 At[2][64][72];
  __shared__ __align__(16) u16 S0T[2][2][32][40];
  __shared__ float K0s[2][32];
  __shared__ float pbv[2][64], ipb[2][64], mixs[2][64], coef[2][64];
  const int ch = blockIdx.x, h = blockIdx.y, b = blockIdx.z;
  const int bh = b*NHH + h;
  const int tid = threadIdx.x;
  const int t0 = ch*CL;
  {
    int j = tid >> 2, oct = tid & 3;
    size_t rb = (size_t)(b*TT + t0 + j)*3072 + h*32 + oct*8;
    u16x8 q8 = *reinterpret_cast<const u16x8*>(qkv + rb);
    u16x8 k8 = *reinterpret_cast<const u16x8*>(qkv + rb + 1024);
    u16x8 v8 = *reinterpret_cast<const u16x8*>(qkv + rb + 2048);
    *reinterpret_cast<u16x8*>(&Qs[j][oct*8]) = q8;
    *reinterpret_cast<u16x8*>(&Ks[j][oct*8]) = k8;
    #pragma unroll
    for (int dd = 0; dd < 8; ++dd) VT[oct*8+dd][j] = v8[dd];
  }
  for (int u = tid; u < 2048; u += 256) {
    int m = u >> 10, r = u & 1023, d = r >> 5, c = r & 31;
    float val = S0g[(((size_t)bh*NCH + ch)*2 + m)*1024 + r];
    u16 hv = f2b(val);
    float lo = val - b2f(hv);
    S0T[m][0][c][d] = hv;
    S0T[m][1][c][d] = f2b(lo);
  }
  if (tid < 64) {
    int m = tid >> 5, d = tid & 31;
    K0s[m][d] = K0g[(((size_t)bh*NCH + ch)*2 + m)*32 + d];
  }
  if (tid < 128) {
    int m = tid & 1, i = tid >> 1;
    float p = pg[(((size_t)bh*NCH + ch)*2 + m)*64 + i];
    pbv[m][i] = p;
    ipb[m][i] = 1.f/p;
  } else if (tid < 192) {
    int i = tid - 128;
    size_t rb = (size_t)(b*TT + t0 + i)*128 + 64 + h*2;
    float a0 = bmraw[rb]   + bmix[h*2];
    float a1 = bmraw[rb+1] + bmix[h*2+1];
    float mx = fmaxf(a0, a1);
    float e0 = expf(a0-mx), e1 = expf(a1-mx);
    float inv = 1.f/(e0+e1);
    mixs[0][i] = e0*inv; mixs[1][i] = e1*inv;
  }
  __syncthreads();
  {
    const int wv = tid >> 6, lane = tid & 63, lr = lane & 15, kg = lane >> 4;
    short8 aq = *reinterpret_cast<const short8*>(&Qs[wv*16 + lr][kg*8]);
    #pragma unroll
    for (int nt = 0; nt < 4; ++nt) {
      short8 bk = *reinterpret_cast<const short8*>(&Ks[nt*16 + lr][kg*8]);
      floatx4 a0 = (floatx4){0.f,0.f,0.f,0.f};
      a0 = __builtin_amdgcn_mfma_f32_16x16x32_bf16(aq, bk, a0, 0, 0, 0);
      int jg = nt*16 + lr;
      float ip0 = ipb[0][jg], ip1 = ipb[1][jg];
      #pragma unroll
      for (int r = 0; r < 4; ++r) {
        int ig = wv*16 + kg*4 + r;
        float val = a0[r];
        bool ok = (jg <= ig);
        At[0][ig][jg] = f2b(ok ? val*ip0 : 0.f);
        At[1][ig][jg] = f2b(ok ? val*ip1 : 0.f);
      }
    }
  }
  __syncthreads();
  if (tid < 128) {
    int m = tid & 1, i = tid >> 1;
    float qK0 = 0.f;
    #pragma unroll
    for (int g = 0; g < 4; ++g) {
      u16x8 qq = *reinterpret_cast<const u16x8*>(&Qs[i][g*8]);
      #pragma unroll
      for (int dd = 0; dd < 8; ++dd) qK0 = fmaf(b2f(qq[dd]), K0s[m][g*8+dd], qK0);
    }
    float As_ = 0.f;
    #pragma unroll
    for (int g = 0; g < 8; ++g) {
      u16x8 aa = *reinterpret_cast<const u16x8*>(&At[m][i][g*8]);
      #pragma unroll
      for (int dd = 0; dd < 8; ++dd) As_ += b2f(aa[dd]);
    }
    float den = pbv[m][i]*(qK0 + As_) + 1e-6f;
    coef[m][i] = mixs[m][i]*pbv[m][i]/den;
  }
  __syncthreads();
  {
    const int wv = tid >> 6, lane = tid & 63, lr = lane & 15, kg = lane >> 4;
    const int i0 = wv*16;
    floatx4 accY[2][2];
    #pragma unroll
    for (int m = 0; m < 2; ++m)
      #pragma unroll
      for (int nt = 0; nt < 2; ++nt)
        accY[m][nt] = (floatx4){0.f,0.f,0.f,0.f};
    short8 aq = *reinterpret_cast<const short8*>(&Qs[i0 + lr][kg*8]);
    #pragma unroll
    for (int m = 0; m < 2; ++m)
      #pragma unroll
      for (int nt = 0; nt < 2; ++nt) {
        short8 bhi = *reinterpret_cast<const short8*>(&S0T[m][0][nt*16 + lr][kg*8]);
        short8 blo = *reinterpret_cast<const short8*>(&S0T[m][1][nt*16 + lr][kg*8]);
        accY[m][nt] = __builtin_amdgcn_mfma_f32_16x16x32_bf16(aq, bhi, accY[m][nt], 0, 0, 0);
        accY[m][nt] = __builtin_amdgcn_mfma_f32_16x16x32_bf16(aq, blo, accY[m][nt], 0, 0, 0);
      }
    #pragma unroll
    for (int ks = 0; ks < 2; ++ks) {
      short8 a0f = *reinterpret_cast<const short8*>(&At[0][i0 + lr][ks*32 + kg*8]);
      short8 a1f = *reinterpret_cast<const short8*>(&At[1][i0 + lr][ks*32 + kg*8]);
      short8 b0 = *reinterpret_cast<const short8*>(&VT[lr][ks*32 + kg*8]);
      short8 b1 = *reinterpret_cast<const short8*>(&VT[16 + lr][ks*32 + kg*8]);
      accY[0][0] = __builtin_amdgcn_mfma_f32_16x16x32_bf16(a0f, b0, accY[0][0], 0, 0, 0);
      accY[0][1] = __builtin_amdgcn_mfma_f32_16x16x32_bf16(a0f, b1, accY[0][1], 0, 0, 0);
      accY[1][0] = __builtin_amdgcn_mfma_f32_16x16x32_bf16(a1f, b0, accY[1][0], 0, 0, 0);
      accY[1][1] = __builtin_amdgcn_mfma_f32_16x16x32_bf16(a1f, b1, accY[1][1], 0, 0, 0);
    }
    #pragma unroll
    for (int r = 0; r < 4; ++r) {
      int i = i0 + kg*4 + r;
      float c0 = coef[0][i], c1 = coef[1][i];
      size_t ob = (size_t)(b*TT + t0 + i)*HH + h*32;
      yb[ob + lr]      = f2b(c0*accY[0][0][r] + c1*accY[1][0][r]);
      yb[ob + 16 + lr] = f2b(c0*accY[0][1][r] + c1*accY[1][1][r]);
    }
  }
}

// ---------------- LayerNorm over rows of z ----------------
__global__ __launch_bounds__(256) void ln_k(
    const float* __restrict__ z, const float* __restrict__ g,
    const float* __restrict__ bta, float* __restrict__ out)
{
  const int row = blockIdx.x;
  const int tid = threadIdx.x;
  size_t o = (size_t)row*HH/4 + tid;
  float4 zv = reinterpret_cast<const float4*>(z)[o];
  float sum = zv.x+zv.y+zv.z+zv.w;
  float sq  = zv.x*zv.x + zv.y*zv.y + zv.z*zv.z + zv.w*zv.w;
  #pragma unroll
  for (int off=1; off<64; off<<=1){ sum += __shfl_xor(sum, off); sq += __shfl_xor(sq, off); }
  __shared__ float s1[4], s2[4];
  int w = tid>>6;
  if ((tid&63)==0){ s1[w]=sum; s2[w]=sq; }
  __syncthreads();
  sum = s1[0]+s1[1]+s1[2]+s1[3];
  sq  = s2[0]+s2[1]+s2[2]+s2[3];
  float mu  = sum * (1.f/1024.f);
  float var = sq * (1.f/1024.f) - mu*mu;
  float rstd = rsqrtf(var + 1e-5f);
  float4 gv = reinterpret_cast<const float4*>(g)[tid];
  float4 bv = reinterpret_cast<const float4*>(bta)[tid];
  float4 ov;
  ov.x = (zv.x-mu)*rstd*gv.x + bv.x;
  ov.y = (zv.y-mu)*rstd*gv.y + bv.y;
  ov.z = (zv.z-mu)*rstd*gv.z + bv.z;
  ov.w = (zv.w-mu)*rstd*gv.w + bv.w;
  reinterpret_cast<float4*>(out)[o] = ov;
}

extern "C" void kernel_launch(void* const* d_in, const int* in_sizes, int n_in,
                              void* d_out, int out_size, void* d_ws, size_t ws_size,
                              hipStream_t stream)
{
  const float* x     = (const float*)d_in[0];
  const float* Wq    = (const float*)d_in[1];
  const float* Wk    = (const float*)d_in[2];
  const float* Wv    = (const float*)d_in[3];
  const float* Wbeta = (const float*)d_in[4];
  const float* bbeta = (const float*)d_in[5];
  const float* Wmix  = (const float*)d_in[6];
  const float* bmix  = (const float*)d_in[7];
  const float* Wout  = (const float*)d_in[8];
  const float* bout  = (const float*)d_in[9];
  const float* ln_g  = (const float*)d_in[10];
  const float* ln_b  = (const float*)d_in[11];
  float* out = (float*)d_out;

  float* ws = (float*)d_ws;
  float* ct      = ws;                       // 16384
  float* st      = ws + 16384;               // 16384
  u16*   x_bf    = (u16*)(ws + 32768);       // 4194304 u16 (reused as y_bf)
  u16*   Wf      = (u16*)(ws + 2129920);     // 3276800 u16
  u16*   Wout_bf = (u16*)(ws + 3768320);     // 1048576 u16
  u16*   qkv     = (u16*)(ws + 4292608);     // 12582912 u16
  float* bmraw   = ws + 10584064;            // 524288
  float* dSS0    = ws + 11108352;            // 4194304 (reused as z)
  float* dKK0    = ws + 15302656;            // 131072
  float* pLg     = ws + 15433728;            // 4096
  float* pg      = ws + 15437824;            // 262144
  u16*   y_bf    = x_bf;
  float* z       = dSS0;

  cast_all_k<<<8320, 256, 0, stream>>>(x, Wq, Wk, Wv, Wbeta, Wmix, Wout,
                                       x_bf, Wf, Wout_bf, ct, st);
  gemm_qkv_k<<<800, 256, 0, stream>>>(x_bf, Wf, ct, st, qkv, bmraw);
  dim3 gscan(NCH, 32, 4);
  scan_delta_k<<<gscan, 256, 0, stream>>>(qkv, bmraw, bbeta, dSS0, dKK0, pLg, pg);
  scan_state_k<<<1024, 256, 0, stream>>>(dSS0, dKK0, pLg);
  scan_apply_k<<<gscan, 256, 0, stream>>>(qkv, bmraw, bmix, dSS0, dKK0, pg, y_bf);
  gemm_out_k<<<512, 256, 0, stream>>>(y_bf, Wout_bf, x, bout, z);
  ln_k<<<4096, 256, 0, stream>>>(z, ln_g, ln_b, out);
}